// Round 1
// baseline (242.527 us; speedup 1.0000x reference)
//
#include <hip/hip_runtime.h>

// NonLocalBlock: B=4, C=256, HID=128, N=64*64=4096, all-f32 in/out.
// Pipeline (all bf16 MFMA 16x16x32, fp32 accum):
//   K1 k_proj  : phiT[b][n][c], thetaT[b][n][c] (transposed), g[b][c][n]
//   K2 k_colsum: colsum[b][m] = sum_n exp(S[n][m]),  S = theta^T phi (atomicAdd)
//   K3 k_attn  : O[b][n][c] = sum_m exp(S[n][m])/colsum[m] * g[c][m]  (flash-style,
//                P goes through LDS to convert C/D layout -> A layout)
//   K4 k_mask  : out = w_mask @ O^T + x
// Workspace: phiT(4MB) thetaT(4MB) g(4MB) colsum(64KB, inverted in place) attng bf16(4MB)

#define NB   4
#define CIN  256
#define HIDN 128
#define NPIX 4096

typedef __attribute__((ext_vector_type(8))) short short8;
typedef __attribute__((ext_vector_type(4))) float f32x4;

__device__ __forceinline__ unsigned short f2bf(float f) {
    unsigned u = __builtin_bit_cast(unsigned, f);
    u += 0x7fffu + ((u >> 16) & 1u);          // RNE; inputs finite
    return (unsigned short)(u >> 16);
}

// ---------------------------------------------------------------- K1: projections
__global__ __launch_bounds__(256) void k_proj(
    const float* __restrict__ x,
    const float* __restrict__ w_phi,
    const float* __restrict__ w_theta,
    const float* __restrict__ w_g,
    unsigned short* __restrict__ phiT,    // [B][N][HID]
    unsigned short* __restrict__ thetaT,  // [B][N][HID]
    unsigned short* __restrict__ gbuf)    // [B][HID][N]
{
    const int nt = blockIdx.x, p = blockIdx.y, b = blockIdx.z;
    const int n0 = nt * 128;
    const float* W = (p == 0) ? w_phi : (p == 1) ? w_theta : w_g;
    const float* X = x + (size_t)b * CIN * NPIX;

    __shared__ alignas(16) unsigned short Ws[128][40];
    __shared__ alignas(16) unsigned short Xs[128][40];

    const int tid = threadIdx.x;
    const int wave = tid >> 6, lane = tid & 63;
    const int wm = wave >> 1, wn = wave & 1;       // 2x2 waves over 128x128 tile
    const int quad = lane >> 4, l16 = lane & 15;

    f32x4 acc[4][4];
#pragma unroll
    for (int i = 0; i < 4; ++i)
#pragma unroll
        for (int j = 0; j < 4; ++j) acc[i][j] = {0.f, 0.f, 0.f, 0.f};

    for (int ks = 0; ks < CIN / 32; ++ks) {
        {   // stage W tile [128 o][32 c], f32 -> bf16
            const int row = tid >> 1, c0 = (tid & 1) * 16;
            const float* src = W + (size_t)row * CIN + ks * 32 + c0;
#pragma unroll
            for (int j = 0; j < 16; ++j) Ws[row][c0 + j] = f2bf(src[j]);
        }
        {   // stage X^T tile: Xs[n][c] from X[c][n]
            const int cc = tid >> 3, nn0 = (tid & 7) * 16;
            const float* src = X + (size_t)(ks * 32 + cc) * NPIX + n0 + nn0;
#pragma unroll
            for (int j = 0; j < 16; ++j) Xs[nn0 + j][cc] = f2bf(src[j]);
        }
        __syncthreads();
#pragma unroll
        for (int mi = 0; mi < 4; ++mi) {
            short8 a = *(const short8*)&Ws[wm * 64 + mi * 16 + l16][quad * 8];
#pragma unroll
            for (int ni = 0; ni < 4; ++ni) {
                short8 bb = *(const short8*)&Xs[wn * 64 + ni * 16 + l16][quad * 8];
                acc[mi][ni] = __builtin_amdgcn_mfma_f32_16x16x32_bf16(a, bb, acc[mi][ni], 0, 0, 0);
            }
        }
        __syncthreads();
    }

    if (p < 2) {   // store transposed: T[b][n][o]
        unsigned short* T = (p == 0) ? phiT : thetaT;
#pragma unroll
        for (int mi = 0; mi < 4; ++mi) {
            const int obase = wm * 64 + mi * 16 + quad * 4;
#pragma unroll
            for (int ni = 0; ni < 4; ++ni) {
                const int nn = wn * 64 + ni * 16 + l16;
                uint2 v;
                v.x = (unsigned)f2bf(acc[mi][ni][0]) | ((unsigned)f2bf(acc[mi][ni][1]) << 16);
                v.y = (unsigned)f2bf(acc[mi][ni][2]) | ((unsigned)f2bf(acc[mi][ni][3]) << 16);
                *(uint2*)&T[((size_t)b * NPIX + n0 + nn) * HIDN + obase] = v;
            }
        }
    } else {       // g stored [b][o][n]
#pragma unroll
        for (int mi = 0; mi < 4; ++mi) {
            const int obase = wm * 64 + mi * 16 + quad * 4;
#pragma unroll
            for (int ni = 0; ni < 4; ++ni) {
                const int nn = wn * 64 + ni * 16 + l16;
#pragma unroll
                for (int r = 0; r < 4; ++r)
                    gbuf[((size_t)b * HIDN + obase + r) * NPIX + n0 + nn] = f2bf(acc[mi][ni][r]);
            }
        }
    }
}

// ---------------------------------------------------------------- K2: column sums of exp(S)
__global__ __launch_bounds__(256) void k_colsum(
    const unsigned short* __restrict__ thetaT,
    const unsigned short* __restrict__ phiT,
    float* __restrict__ colsum)
{
    const int mt = blockIdx.x, nt = blockIdx.y, b = blockIdx.z;
    const int m0 = mt * 128, n0 = nt * 128;
    __shared__ alignas(16) unsigned short As[128][40];
    __shared__ alignas(16) unsigned short Bs[128][40];
    const int tid = threadIdx.x;
    const int wave = tid >> 6, lane = tid & 63;
    const int wm = wave >> 1, wn = wave & 1;
    const int quad = lane >> 4, l16 = lane & 15;

    f32x4 acc[4][4];
#pragma unroll
    for (int i = 0; i < 4; ++i)
#pragma unroll
        for (int j = 0; j < 4; ++j) acc[i][j] = {0.f, 0.f, 0.f, 0.f};

    for (int ks = 0; ks < 4; ++ks) {
#pragma unroll
        for (int j = 0; j < 2; ++j) {
            const int idx = j * 256 + tid;
            const int row = idx >> 2, cc = (idx & 3) * 8;
            *(uint4*)&As[row][cc] =
                *(const uint4*)&thetaT[((size_t)b * NPIX + n0 + row) * HIDN + ks * 32 + cc];
            *(uint4*)&Bs[row][cc] =
                *(const uint4*)&phiT[((size_t)b * NPIX + m0 + row) * HIDN + ks * 32 + cc];
        }
        __syncthreads();
#pragma unroll
        for (int mi = 0; mi < 4; ++mi) {
            short8 a = *(const short8*)&As[wm * 64 + mi * 16 + l16][quad * 8];
#pragma unroll
            for (int ni = 0; ni < 4; ++ni) {
                short8 bb = *(const short8*)&Bs[wn * 64 + ni * 16 + l16][quad * 8];
                acc[mi][ni] = __builtin_amdgcn_mfma_f32_16x16x32_bf16(a, bb, acc[mi][ni], 0, 0, 0);
            }
        }
        __syncthreads();
    }

#pragma unroll
    for (int ni = 0; ni < 4; ++ni) {
        float s = 0.f;
#pragma unroll
        for (int mi = 0; mi < 4; ++mi)
#pragma unroll
            for (int r = 0; r < 4; ++r) s += __expf(acc[mi][ni][r]);
        s += __shfl_xor(s, 16);   // combine quads (rows partitioned over quad)
        s += __shfl_xor(s, 32);
        if (quad == 0)
            atomicAdd(&colsum[(size_t)b * NPIX + m0 + wn * 64 + ni * 16 + l16], s);
    }
}

__global__ void k_zero(float* __restrict__ p) { p[blockIdx.x * 256 + threadIdx.x] = 0.f; }
__global__ void k_inv(float* __restrict__ p) {
    const int i = blockIdx.x * 256 + threadIdx.x;
    p[i] = 1.0f / p[i];
}

// ---------------------------------------------------------------- K3: O = softmax-attn @ g^T
__global__ __launch_bounds__(256) void k_attn(
    const unsigned short* __restrict__ thetaT,
    const unsigned short* __restrict__ phiT,
    const unsigned short* __restrict__ gbuf,
    const float* __restrict__ invcs,
    unsigned short* __restrict__ attng)   // [B][N][HID] bf16
{
    const int nt = blockIdx.x, b = blockIdx.y;
    const int n0 = nt * 64;
    __shared__ alignas(16) unsigned short As[64][136];   // theta tile, full K=128
    __shared__ alignas(16) unsigned short Bs[64][136];   // phi chunk [m][c]
    __shared__ alignas(16) unsigned short Ps[64][72];    // P chunk  [n][m]
    __shared__ alignas(16) unsigned short Gs[128][72];   // g chunk  [c][m]
    const int tid = threadIdx.x;
    const int wave = tid >> 6, lane = tid & 63;
    const int wm = wave >> 1, wn = wave & 1;
    const int quad = lane >> 4, l16 = lane & 15;

#pragma unroll
    for (int j = 0; j < 4; ++j) {   // stage As once (64 rows x 128)
        const int idx = j * 256 + tid;
        const int row = idx >> 4, cc = (idx & 15) * 8;
        *(uint4*)&As[row][cc] =
            *(const uint4*)&thetaT[((size_t)b * NPIX + n0 + row) * HIDN + cc];
    }

    f32x4 accO[2][4];
#pragma unroll
    for (int i = 0; i < 2; ++i)
#pragma unroll
        for (int j = 0; j < 4; ++j) accO[i][j] = {0.f, 0.f, 0.f, 0.f};

    for (int mc = 0; mc < 64; ++mc) {
        const int m0 = mc * 64;
        __syncthreads();   // prev PV done (and As staged on mc==0)
#pragma unroll
        for (int j = 0; j < 4; ++j) {   // stage phi chunk [64 m][128 c]
            const int idx = j * 256 + tid;
            const int row = idx >> 4, cc = (idx & 15) * 8;
            *(uint4*)&Bs[row][cc] =
                *(const uint4*)&phiT[((size_t)b * NPIX + m0 + row) * HIDN + cc];
        }
#pragma unroll
        for (int j = 0; j < 4; ++j) {   // stage g chunk [128 c][64 m]
            const int idx = j * 256 + tid;
            const int row = idx >> 3, cc = (idx & 7) * 8;
            *(uint4*)&Gs[row][cc] =
                *(const uint4*)&gbuf[((size_t)b * HIDN + row) * NPIX + m0 + cc];
        }
        __syncthreads();

        f32x4 accS[2][2];
#pragma unroll
        for (int i = 0; i < 2; ++i)
#pragma unroll
            for (int j = 0; j < 2; ++j) accS[i][j] = {0.f, 0.f, 0.f, 0.f};

#pragma unroll
        for (int ks = 0; ks < 4; ++ks) {   // S tile [64 n][64 m], K=128
#pragma unroll
            for (int mi = 0; mi < 2; ++mi) {
                short8 a = *(const short8*)&As[wm * 32 + mi * 16 + l16][ks * 32 + quad * 8];
#pragma unroll
                for (int ni = 0; ni < 2; ++ni) {
                    short8 bb = *(const short8*)&Bs[wn * 32 + ni * 16 + l16][ks * 32 + quad * 8];
                    accS[mi][ni] = __builtin_amdgcn_mfma_f32_16x16x32_bf16(a, bb, accS[mi][ni], 0, 0, 0);
                }
            }
        }
        // P = exp(S) * 1/colsum[m]  -> LDS (C/D layout -> A layout round-trip)
#pragma unroll
        for (int ni = 0; ni < 2; ++ni) {
            const int mcol = wn * 32 + ni * 16 + l16;
            const float inv = invcs[(size_t)b * NPIX + m0 + mcol];
#pragma unroll
            for (int mi = 0; mi < 2; ++mi)
#pragma unroll
                for (int r = 0; r < 4; ++r) {
                    const float pv = __expf(accS[mi][ni][r]) * inv;
                    Ps[wm * 32 + mi * 16 + quad * 4 + r][mcol] = f2bf(pv);
                }
        }
        __syncthreads();
#pragma unroll
        for (int ks = 0; ks < 2; ++ks) {   // O tile [64 n][128 c], K=64 (m chunk)
#pragma unroll
            for (int mi = 0; mi < 2; ++mi) {
                short8 a = *(const short8*)&Ps[wm * 32 + mi * 16 + l16][ks * 32 + quad * 8];
#pragma unroll
                for (int ni = 0; ni < 4; ++ni) {
                    short8 bb = *(const short8*)&Gs[wn * 64 + ni * 16 + l16][ks * 32 + quad * 8];
                    accO[mi][ni] = __builtin_amdgcn_mfma_f32_16x16x32_bf16(a, bb, accO[mi][ni], 0, 0, 0);
                }
            }
        }
    }

#pragma unroll
    for (int mi = 0; mi < 2; ++mi)
#pragma unroll
        for (int ni = 0; ni < 4; ++ni)
#pragma unroll
            for (int r = 0; r < 4; ++r) {
                const int nrow = wm * 32 + mi * 16 + quad * 4 + r;
                const int ccol = wn * 64 + ni * 16 + l16;
                attng[((size_t)b * NPIX + n0 + nrow) * HIDN + ccol] = f2bf(accO[mi][ni][r]);
            }
}

// ---------------------------------------------------------------- K4: mask GEMM + residual
__global__ __launch_bounds__(256) void k_mask(
    const float* __restrict__ w_mask,            // [256][128]
    const unsigned short* __restrict__ attng,    // [B][N][HID] bf16
    const float* __restrict__ x,
    float* __restrict__ out)
{
    const int nt = blockIdx.x, ct = blockIdx.y, b = blockIdx.z;
    const int n0 = nt * 128, c0 = ct * 128;
    __shared__ alignas(16) unsigned short As[128][40];
    __shared__ alignas(16) unsigned short Bs[128][40];
    const int tid = threadIdx.x;
    const int wave = tid >> 6, lane = tid & 63;
    const int wm = wave >> 1, wn = wave & 1;
    const int quad = lane >> 4, l16 = lane & 15;

    f32x4 acc[4][4];
#pragma unroll
    for (int i = 0; i < 4; ++i)
#pragma unroll
        for (int j = 0; j < 4; ++j) acc[i][j] = {0.f, 0.f, 0.f, 0.f};

    for (int ks = 0; ks < 4; ++ks) {
        {   // A: w_mask tile [128 co][32 h], f32 -> bf16
            const int row = tid >> 1, cc0 = (tid & 1) * 16;
            const float* src = w_mask + (size_t)(c0 + row) * HIDN + ks * 32 + cc0;
#pragma unroll
            for (int j = 0; j < 16; ++j) As[row][cc0 + j] = f2bf(src[j]);
        }
#pragma unroll
        for (int j = 0; j < 2; ++j) {   // B: attng tile [128 n][32 h] bf16 direct
            const int idx = j * 256 + tid;
            const int row = idx >> 2, cc = (idx & 3) * 8;
            *(uint4*)&Bs[row][cc] =
                *(const uint4*)&attng[((size_t)b * NPIX + n0 + row) * HIDN + ks * 32 + cc];
        }
        __syncthreads();
#pragma unroll
        for (int mi = 0; mi < 4; ++mi) {
            short8 a = *(const short8*)&As[wm * 64 + mi * 16 + l16][quad * 8];
#pragma unroll
            for (int ni = 0; ni < 4; ++ni) {
                short8 bb = *(const short8*)&Bs[wn * 64 + ni * 16 + l16][quad * 8];
                acc[mi][ni] = __builtin_amdgcn_mfma_f32_16x16x32_bf16(a, bb, acc[mi][ni], 0, 0, 0);
            }
        }
        __syncthreads();
    }

#pragma unroll
    for (int mi = 0; mi < 4; ++mi)
#pragma unroll
        for (int ni = 0; ni < 4; ++ni)
#pragma unroll
            for (int r = 0; r < 4; ++r) {
                const int co = c0 + wm * 64 + mi * 16 + quad * 4 + r;
                const int nn = n0 + wn * 64 + ni * 16 + l16;
                const size_t idx = ((size_t)b * CIN + co) * NPIX + nn;
                out[idx] = acc[mi][ni][r] + x[idx];
            }
}

// ---------------------------------------------------------------- launch
extern "C" void kernel_launch(void* const* d_in, const int* in_sizes, int n_in,
                              void* d_out, int out_size, void* d_ws, size_t ws_size,
                              hipStream_t stream)
{
    (void)in_sizes; (void)n_in; (void)out_size; (void)ws_size;
    const float* x       = (const float*)d_in[0];
    const float* w_phi   = (const float*)d_in[1];
    const float* w_theta = (const float*)d_in[2];
    const float* w_g     = (const float*)d_in[3];
    const float* w_mask  = (const float*)d_in[4];
    float* out = (float*)d_out;

    char* ws = (char*)d_ws;
    unsigned short* phiT   = (unsigned short*)(ws);              //  4 MB
    unsigned short* thetaT = (unsigned short*)(ws + 4194304);    //  4 MB
    unsigned short* gbuf   = (unsigned short*)(ws + 8388608);    //  4 MB
    float*          colsum = (float*)(ws + 12582912);            // 64 KB (inverted in place)
    unsigned short* attng  = (unsigned short*)(ws + 12648448);   //  4 MB
    // total ws use: 16,842,752 bytes

    k_proj  <<<dim3(32, 3, 4),  256, 0, stream>>>(x, w_phi, w_theta, w_g, phiT, thetaT, gbuf);
    k_zero  <<<dim3(64),        256, 0, stream>>>(colsum);
    k_colsum<<<dim3(32, 32, 4), 256, 0, stream>>>(thetaT, phiT, colsum);
    k_inv   <<<dim3(64),        256, 0, stream>>>(colsum);
    k_attn  <<<dim3(64, 4),     256, 0, stream>>>(thetaT, phiT, gbuf, colsum, attng);
    k_mask  <<<dim3(32, 2, 4),  256, 0, stream>>>(w_mask, attng, x, out);
}

// Round 2
// 200.527 us; speedup vs baseline: 1.2094x; 1.2094x over previous
//
#include <hip/hip_runtime.h>

// NonLocalBlock: B=4, C=256, HID=128, N=64*64=4096, all-f32 in/out.
// Pipeline (all bf16 MFMA 16x16x32, fp32 accum):
//   K1 k_proj   : phiT[b][n][c], thetaT[b][n][c] (transposed), g[b][c][n]
//   K2 k_colsum : colsum[b][m] = sum_n exp(S[n][m]),  S = theta^T phi
//   K2b k_scale_g: g[c][m] *= 1/colsum[m]   (fold softmax denom into g)
//   K3 k_attn   : O32[b][n][c] += sum_m exp(S[n][m]) * g'[c][m]
//                 (m-split x3 across blocks, fp32 atomic accumulate;
//                  theta A-frags register-resident; P via LDS round-trip)
//   K4 k_mask   : out = w_mask @ O^T + x    (O32 fp32 -> bf16 at staging)
// ws: phiT(4M) thetaT(4M) gbuf(4M) colsum(64K) O32(8M) = 21.04 MB

#define NB   4
#define CIN  256
#define HIDN 128
#define NPIX 4096

typedef __attribute__((ext_vector_type(8))) short short8;
typedef __attribute__((ext_vector_type(4))) float f32x4;

__device__ __forceinline__ unsigned short f2bf(float f) {
    unsigned u = __builtin_bit_cast(unsigned, f);
    u += 0x7fffu + ((u >> 16) & 1u);          // RNE; inputs finite
    return (unsigned short)(u >> 16);
}
__device__ __forceinline__ float bf2f(unsigned short s) {
    return __builtin_bit_cast(float, (unsigned)s << 16);
}

// ---------------------------------------------------------------- K1: projections
__global__ __launch_bounds__(256) void k_proj(
    const float* __restrict__ x,
    const float* __restrict__ w_phi,
    const float* __restrict__ w_theta,
    const float* __restrict__ w_g,
    unsigned short* __restrict__ phiT,    // [B][N][HID]
    unsigned short* __restrict__ thetaT,  // [B][N][HID]
    unsigned short* __restrict__ gbuf)    // [B][HID][N]
{
    const int nt = blockIdx.x, p = blockIdx.y, b = blockIdx.z;
    const int n0 = nt * 128;
    const float* W = (p == 0) ? w_phi : (p == 1) ? w_theta : w_g;
    const float* X = x + (size_t)b * CIN * NPIX;

    __shared__ alignas(16) unsigned short Ws[128][40];
    __shared__ alignas(16) unsigned short Xs[128][40];

    const int tid = threadIdx.x;
    const int wave = tid >> 6, lane = tid & 63;
    const int wm = wave >> 1, wn = wave & 1;       // 2x2 waves over 128x128 tile
    const int quad = lane >> 4, l16 = lane & 15;

    f32x4 acc[4][4];
#pragma unroll
    for (int i = 0; i < 4; ++i)
#pragma unroll
        for (int j = 0; j < 4; ++j) acc[i][j] = {0.f, 0.f, 0.f, 0.f};

    for (int ks = 0; ks < CIN / 32; ++ks) {
        {   // stage W tile [128 o][32 c], f32 -> bf16
            const int row = tid >> 1, c0 = (tid & 1) * 16;
            const float* src = W + (size_t)row * CIN + ks * 32 + c0;
#pragma unroll
            for (int j = 0; j < 16; ++j) Ws[row][c0 + j] = f2bf(src[j]);
        }
        {   // stage X^T tile: Xs[n][c] from X[c][n]
            const int cc = tid >> 3, nn0 = (tid & 7) * 16;
            const float* src = X + (size_t)(ks * 32 + cc) * NPIX + n0 + nn0;
#pragma unroll
            for (int j = 0; j < 16; ++j) Xs[nn0 + j][cc] = f2bf(src[j]);
        }
        __syncthreads();
#pragma unroll
        for (int mi = 0; mi < 4; ++mi) {
            short8 a = *(const short8*)&Ws[wm * 64 + mi * 16 + l16][quad * 8];
#pragma unroll
            for (int ni = 0; ni < 4; ++ni) {
                short8 bb = *(const short8*)&Xs[wn * 64 + ni * 16 + l16][quad * 8];
                acc[mi][ni] = __builtin_amdgcn_mfma_f32_16x16x32_bf16(a, bb, acc[mi][ni], 0, 0, 0);
            }
        }
        __syncthreads();
    }

    if (p < 2) {   // store transposed: T[b][n][o]
        unsigned short* T = (p == 0) ? phiT : thetaT;
#pragma unroll
        for (int mi = 0; mi < 4; ++mi) {
            const int obase = wm * 64 + mi * 16 + quad * 4;
#pragma unroll
            for (int ni = 0; ni < 4; ++ni) {
                const int nn = wn * 64 + ni * 16 + l16;
                uint2 v;
                v.x = (unsigned)f2bf(acc[mi][ni][0]) | ((unsigned)f2bf(acc[mi][ni][1]) << 16);
                v.y = (unsigned)f2bf(acc[mi][ni][2]) | ((unsigned)f2bf(acc[mi][ni][3]) << 16);
                *(uint2*)&T[((size_t)b * NPIX + n0 + nn) * HIDN + obase] = v;
            }
        }
    } else {       // g stored [b][o][n]
#pragma unroll
        for (int mi = 0; mi < 4; ++mi) {
            const int obase = wm * 64 + mi * 16 + quad * 4;
#pragma unroll
            for (int ni = 0; ni < 4; ++ni) {
                const int nn = wn * 64 + ni * 16 + l16;
#pragma unroll
                for (int r = 0; r < 4; ++r)
                    gbuf[((size_t)b * HIDN + obase + r) * NPIX + n0 + nn] = f2bf(acc[mi][ni][r]);
            }
        }
    }
}

// ---------------------------------------------------------------- K2: column sums of exp(S)
// grid (mt=32, ntg=8, b=4). phi tile staged ONCE, 4 theta chunks looped.
__global__ __launch_bounds__(256, 2) void k_colsum(
    const unsigned short* __restrict__ thetaT,
    const unsigned short* __restrict__ phiT,
    float* __restrict__ colsum)
{
    const int mt = blockIdx.x, ntg = blockIdx.y, b = blockIdx.z;
    const int m0 = mt * 128;
    __shared__ alignas(16) unsigned short As[128][136];   // theta [n][k]
    __shared__ alignas(16) unsigned short Bs[128][136];   // phi   [m][k]
    const int tid = threadIdx.x;
    const int wave = tid >> 6, lane = tid & 63;
    const int wm = wave >> 1, wn = wave & 1;
    const int quad = lane >> 4, l16 = lane & 15;

#pragma unroll
    for (int i = 0; i < 8; ++i) {   // stage phi once (full K=128)
        const int idx = i * 256 + tid;
        const int row = idx >> 4, cc = (idx & 15) * 8;
        *(uint4*)&Bs[row][cc] =
            *(const uint4*)&phiT[((size_t)b * NPIX + m0 + row) * HIDN + cc];
    }

    float csum[4] = {0.f, 0.f, 0.f, 0.f};

    for (int nc = 0; nc < 4; ++nc) {
        const int n0 = ntg * 512 + nc * 128;
        __syncthreads();   // prev MFMA done reading As (and Bs staged, nc==0)
#pragma unroll
        for (int i = 0; i < 8; ++i) {
            const int idx = i * 256 + tid;
            const int row = idx >> 4, cc = (idx & 15) * 8;
            *(uint4*)&As[row][cc] =
                *(const uint4*)&thetaT[((size_t)b * NPIX + n0 + row) * HIDN + cc];
        }
        __syncthreads();

        f32x4 acc[4][4];
#pragma unroll
        for (int i = 0; i < 4; ++i)
#pragma unroll
            for (int j = 0; j < 4; ++j) acc[i][j] = {0.f, 0.f, 0.f, 0.f};

#pragma unroll
        for (int ks = 0; ks < 4; ++ks) {
            short8 af[4], bf[4];
#pragma unroll
            for (int mi = 0; mi < 4; ++mi)
                af[mi] = *(const short8*)&As[wm * 64 + mi * 16 + l16][ks * 32 + quad * 8];
#pragma unroll
            for (int ni = 0; ni < 4; ++ni)
                bf[ni] = *(const short8*)&Bs[wn * 64 + ni * 16 + l16][ks * 32 + quad * 8];
#pragma unroll
            for (int mi = 0; mi < 4; ++mi)
#pragma unroll
                for (int ni = 0; ni < 4; ++ni)
                    acc[mi][ni] = __builtin_amdgcn_mfma_f32_16x16x32_bf16(af[mi], bf[ni], acc[mi][ni], 0, 0, 0);
        }
#pragma unroll
        for (int ni = 0; ni < 4; ++ni)
#pragma unroll
            for (int mi = 0; mi < 4; ++mi)
#pragma unroll
                for (int r = 0; r < 4; ++r) csum[ni] += __expf(acc[mi][ni][r]);
    }

#pragma unroll
    for (int ni = 0; ni < 4; ++ni) {
        float s = csum[ni];
        s += __shfl_xor(s, 16);   // combine quads (n partitioned over quad/reg)
        s += __shfl_xor(s, 32);
        if (quad == 0)
            atomicAdd(&colsum[(size_t)b * NPIX + m0 + wn * 64 + ni * 16 + l16], s);
    }
}

__global__ void k_zero(float* __restrict__ p) { p[blockIdx.x * 256 + threadIdx.x] = 0.f; }
__global__ void k_zero4(float* __restrict__ p) {
    const size_t i = (size_t)(blockIdx.x * 256 + threadIdx.x) * 4;
    *(f32x4*)&p[i] = f32x4{0.f, 0.f, 0.f, 0.f};
}

// ---------------------------------------------------------------- K2b: g[c][m] *= 1/colsum[m]
__global__ __launch_bounds__(256) void k_scale_g(
    unsigned short* __restrict__ gbuf, const float* __restrict__ colsum)
{
    const int idx = blockIdx.x * 256 + threadIdx.x;   // 262144 total
    const int row = idx >> 9;                          // 0..511 = b*128+c
    const int m0 = (idx & 511) * 8;
    const int b = row >> 7;
    uint4 v = *(uint4*)&gbuf[(size_t)row * NPIX + m0];
    float4 c0 = *(const float4*)&colsum[(size_t)b * NPIX + m0];
    float4 c1 = *(const float4*)&colsum[(size_t)b * NPIX + m0 + 4];
    unsigned short* vs = (unsigned short*)&v;
    const float cs[8] = {c0.x, c0.y, c0.z, c0.w, c1.x, c1.y, c1.z, c1.w};
#pragma unroll
    for (int j = 0; j < 8; ++j) vs[j] = f2bf(bf2f(vs[j]) / cs[j]);
    *(uint4*)&gbuf[(size_t)row * NPIX + m0] = v;
}

// ---------------------------------------------------------------- K3: O += exp(S) @ g'^T
// grid (nt=64, ms=3, b=4) = 768 blocks = 3/CU. m chunks split 22/21/21.
__global__ __launch_bounds__(256, 3) void k_attn(
    const unsigned short* __restrict__ thetaT,
    const unsigned short* __restrict__ phiT,
    const unsigned short* __restrict__ gbuf,   // pre-scaled by 1/colsum
    float* __restrict__ O32)                   // [B][N][HID] fp32, zeroed
{
    const int nt = blockIdx.x, ms = blockIdx.y, b = blockIdx.z;
    const int n0 = nt * 64;
    const int mstart = ms ? (21 * ms + 1) : 0;
    const int mcount = ms ? 21 : 22;

    __shared__ alignas(16) unsigned short Bs[64][136];   // phi chunk [m][k]
    __shared__ alignas(16) unsigned short Gs[128][72];   // g'  chunk [c][m]
    __shared__ alignas(16) unsigned short Ps[64][72];    // P   chunk [n][m]

    const int tid = threadIdx.x;
    const int wave = tid >> 6, lane = tid & 63;
    const int wm = wave >> 1, wn = wave & 1;
    const int quad = lane >> 4, l16 = lane & 15;

    // theta A-fragments register-resident (rows n0+wm*32 .. +32, full K=128)
    short8 afrag[2][4];
#pragma unroll
    for (int mi = 0; mi < 2; ++mi) {
        const unsigned short* src =
            thetaT + ((size_t)b * NPIX + n0 + wm * 32 + mi * 16 + l16) * HIDN + quad * 8;
#pragma unroll
        for (int ks = 0; ks < 4; ++ks) afrag[mi][ks] = *(const short8*)(src + ks * 32);
    }

    f32x4 accO[2][4];
#pragma unroll
    for (int i = 0; i < 2; ++i)
#pragma unroll
        for (int j = 0; j < 4; ++j) accO[i][j] = {0.f, 0.f, 0.f, 0.f};

    for (int mc = 0; mc < mcount; ++mc) {
        const int m0 = (mstart + mc) * 64;
        __syncthreads();   // prev PV done reading Gs/Ps; prev S done reading Bs
#pragma unroll
        for (int j = 0; j < 4; ++j) {   // stage phi chunk [64 m][128 k]
            const int idx = j * 256 + tid;
            const int row = idx >> 4, cc = (idx & 15) * 8;
            *(uint4*)&Bs[row][cc] =
                *(const uint4*)&phiT[((size_t)b * NPIX + m0 + row) * HIDN + cc];
        }
#pragma unroll
        for (int j = 0; j < 4; ++j) {   // stage g' chunk [128 c][64 m]
            const int idx = j * 256 + tid;
            const int row = idx >> 3, cc = (idx & 7) * 8;
            *(uint4*)&Gs[row][cc] =
                *(const uint4*)&gbuf[((size_t)b * HIDN + row) * NPIX + m0 + cc];
        }
        __syncthreads();

        f32x4 accS[2][2];
#pragma unroll
        for (int i = 0; i < 2; ++i)
#pragma unroll
            for (int j = 0; j < 2; ++j) accS[i][j] = {0.f, 0.f, 0.f, 0.f};

#pragma unroll
        for (int ks = 0; ks < 4; ++ks) {   // S tile [64 n][64 m], K=128
            short8 bf[2];
#pragma unroll
            for (int ni = 0; ni < 2; ++ni)
                bf[ni] = *(const short8*)&Bs[wn * 32 + ni * 16 + l16][ks * 32 + quad * 8];
#pragma unroll
            for (int mi = 0; mi < 2; ++mi)
#pragma unroll
                for (int ni = 0; ni < 2; ++ni)
                    accS[mi][ni] = __builtin_amdgcn_mfma_f32_16x16x32_bf16(
                        afrag[mi][ks], bf[ni], accS[mi][ni], 0, 0, 0);
        }
        // P = exp(S) -> LDS (C/D layout -> A layout round-trip)
#pragma unroll
        for (int ni = 0; ni < 2; ++ni) {
            const int mcol = wn * 32 + ni * 16 + l16;
#pragma unroll
            for (int mi = 0; mi < 2; ++mi)
#pragma unroll
                for (int r = 0; r < 4; ++r)
                    Ps[wm * 32 + mi * 16 + quad * 4 + r][mcol] = f2bf(__expf(accS[mi][ni][r]));
        }
        __syncthreads();
#pragma unroll
        for (int ks = 0; ks < 2; ++ks) {   // O tile [64 n][128 c], K=64 (m chunk)
            short8 pa[2], gb[4];
#pragma unroll
            for (int mi = 0; mi < 2; ++mi)
                pa[mi] = *(const short8*)&Ps[wm * 32 + mi * 16 + l16][ks * 32 + quad * 8];
#pragma unroll
            for (int ni = 0; ni < 4; ++ni)
                gb[ni] = *(const short8*)&Gs[wn * 64 + ni * 16 + l16][ks * 32 + quad * 8];
#pragma unroll
            for (int mi = 0; mi < 2; ++mi)
#pragma unroll
                for (int ni = 0; ni < 4; ++ni)
                    accO[mi][ni] = __builtin_amdgcn_mfma_f32_16x16x32_bf16(
                        pa[mi], gb[ni], accO[mi][ni], 0, 0, 0);
        }
    }

#pragma unroll
    for (int mi = 0; mi < 2; ++mi)
#pragma unroll
        for (int ni = 0; ni < 4; ++ni)
#pragma unroll
            for (int r = 0; r < 4; ++r) {
                const int nrow = n0 + wm * 32 + mi * 16 + quad * 4 + r;
                const int ccol = wn * 64 + ni * 16 + l16;
                atomicAdd(&O32[((size_t)b * NPIX + nrow) * HIDN + ccol], accO[mi][ni][r]);
            }
}

// ---------------------------------------------------------------- K4: mask GEMM + residual
__global__ __launch_bounds__(256) void k_mask(
    const float* __restrict__ w_mask,      // [256][128]
    const float* __restrict__ O32,         // [B][N][HID] fp32
    const float* __restrict__ x,
    float* __restrict__ out)
{
    const int nt = blockIdx.x, ct = blockIdx.y, b = blockIdx.z;
    const int n0 = nt * 128, c0 = ct * 128;
    __shared__ alignas(16) unsigned short As[128][40];
    __shared__ alignas(16) unsigned short Bs[128][40];
    const int tid = threadIdx.x;
    const int wave = tid >> 6, lane = tid & 63;
    const int wm = wave >> 1, wn = wave & 1;
    const int quad = lane >> 4, l16 = lane & 15;

    f32x4 acc[4][4];
#pragma unroll
    for (int i = 0; i < 4; ++i)
#pragma unroll
        for (int j = 0; j < 4; ++j) acc[i][j] = {0.f, 0.f, 0.f, 0.f};

    for (int ks = 0; ks < 4; ++ks) {
        {   // A: w_mask tile [128 co][32 h], f32 -> bf16
            const int row = tid >> 1, cc0 = (tid & 1) * 16;
            const float* src = w_mask + (size_t)(c0 + row) * HIDN + ks * 32 + cc0;
#pragma unroll
            for (int j = 0; j < 16; ++j) As[row][cc0 + j] = f2bf(src[j]);
        }
        {   // B: O32 tile [128 n][32 h], f32 -> bf16
            const int row = tid >> 1, h0 = (tid & 1) * 16;
            const float* src = O32 + ((size_t)b * NPIX + n0 + row) * HIDN + ks * 32 + h0;
#pragma unroll
            for (int j = 0; j < 16; ++j) Bs[row][h0 + j] = f2bf(src[j]);
        }
        __syncthreads();
#pragma unroll
        for (int mi = 0; mi < 4; ++mi) {
            short8 a = *(const short8*)&As[wm * 64 + mi * 16 + l16][quad * 8];
#pragma unroll
            for (int ni = 0; ni < 4; ++ni) {
                short8 bb = *(const short8*)&Bs[wn * 64 + ni * 16 + l16][quad * 8];
                acc[mi][ni] = __builtin_amdgcn_mfma_f32_16x16x32_bf16(a, bb, acc[mi][ni], 0, 0, 0);
            }
        }
        __syncthreads();
    }

#pragma unroll
    for (int mi = 0; mi < 4; ++mi)
#pragma unroll
        for (int ni = 0; ni < 4; ++ni)
#pragma unroll
            for (int r = 0; r < 4; ++r) {
                const int co = c0 + wm * 64 + mi * 16 + quad * 4 + r;
                const int nn = n0 + wn * 64 + ni * 16 + l16;
                const size_t idx = ((size_t)b * CIN + co) * NPIX + nn;
                out[idx] = acc[mi][ni][r] + x[idx];
            }
}

// ---------------------------------------------------------------- launch
extern "C" void kernel_launch(void* const* d_in, const int* in_sizes, int n_in,
                              void* d_out, int out_size, void* d_ws, size_t ws_size,
                              hipStream_t stream)
{
    (void)in_sizes; (void)n_in; (void)out_size; (void)ws_size;
    const float* x       = (const float*)d_in[0];
    const float* w_phi   = (const float*)d_in[1];
    const float* w_theta = (const float*)d_in[2];
    const float* w_g     = (const float*)d_in[3];
    const float* w_mask  = (const float*)d_in[4];
    float* out = (float*)d_out;

    char* ws = (char*)d_ws;
    unsigned short* phiT   = (unsigned short*)(ws);              //  4 MB
    unsigned short* thetaT = (unsigned short*)(ws + 4194304);    //  4 MB
    unsigned short* gbuf   = (unsigned short*)(ws + 8388608);    //  4 MB
    float*          colsum = (float*)(ws + 12582912);            // 64 KB
    float*          O32    = (float*)(ws + 12648448);            //  8 MB
    // total ws use: 21,037,056 bytes

    k_proj   <<<dim3(32, 3, 4), 256, 0, stream>>>(x, w_phi, w_theta, w_g, phiT, thetaT, gbuf);
    k_zero   <<<dim3(64),       256, 0, stream>>>(colsum);
    k_zero4  <<<dim3(2048),     256, 0, stream>>>(O32);
    k_colsum <<<dim3(32, 8, 4), 256, 0, stream>>>(thetaT, phiT, colsum);
    k_scale_g<<<dim3(1024),     256, 0, stream>>>(gbuf, colsum);
    k_attn   <<<dim3(64, 3, 4), 256, 0, stream>>>(thetaT, phiT, gbuf, O32);
    k_mask   <<<dim3(32, 2, 4), 256, 0, stream>>>(w_mask, O32, x, out);
}

// Round 3
// 186.521 us; speedup vs baseline: 1.3003x; 1.0751x over previous
//
#include <hip/hip_runtime.h>

// NonLocalBlock: B=4, C=256, HID=128, N=64*64=4096, all-f32 in/out.
// Pipeline (bf16 MFMA, fp32 accum):
//   K1 k_proj   : phiT[b][n][c], thetaT[b][n][c], g[b][c][n]  (granule-XOR swizzled)
//   K2 k_colsum : colsum[b][m] = sum_n exp(S[n][m])      (DMA-staged, 16x16 core)
//   K2b k_scale_g: g[c][m] *= 1/colsum[m]
//   K3 k_attn   : O32[b][n][c] += sum_m exp(S[n][m]) * g'[c][m]
//                 (32x32x16 MFMA, 128-m chunks, global_load_lds staging,
//                  register A-frags, swizzled Ps round-trip, m-split x2 + atomics)
//   K4 k_mask   : out = w_mask @ O^T + x
// Swizzle convention for bf16 buffers: element (row r, col c) stored at column
//   (c & ~127) | ((((c>>3)&15) ^ (r&15)) << 3) | (c&7)
// -> DMA-staged LDS tiles give conflict-free ds_read_b128 fragment reads.
// ws: phiT(4M) thetaT(4M) gbuf(4M) colsum(64K) O32(8M) = 21.04 MB

#define NB   4
#define CIN  256
#define HIDN 128
#define NPIX 4096

typedef __attribute__((ext_vector_type(8))) short short8;
typedef __attribute__((ext_vector_type(4))) float f32x4;
typedef __attribute__((ext_vector_type(16))) float f32x16;

__device__ __forceinline__ unsigned short f2bf(float f) {
    unsigned u = __builtin_bit_cast(unsigned, f);
    u += 0x7fffu + ((u >> 16) & 1u);          // RNE; inputs finite
    return (unsigned short)(u >> 16);
}
__device__ __forceinline__ unsigned f2bf2(float lo, float hi) {
    return (unsigned)f2bf(lo) | ((unsigned)f2bf(hi) << 16);
}
__device__ __forceinline__ float bf2f(unsigned short s) {
    return __builtin_bit_cast(float, (unsigned)s << 16);
}
// async global->LDS, 16B per lane; LDS dest must be wave-uniform base + lane*16
__device__ __forceinline__ void cp16(void* lds, const void* g) {
    __builtin_amdgcn_global_load_lds(
        (const __attribute__((address_space(1))) unsigned int*)g,
        (__attribute__((address_space(3))) unsigned int*)lds, 16, 0, 0);
}

// ---------------------------------------------------------------- K1: projections
__global__ __launch_bounds__(256) void k_proj(
    const float* __restrict__ x,
    const float* __restrict__ w_phi,
    const float* __restrict__ w_theta,
    const float* __restrict__ w_g,
    unsigned short* __restrict__ phiT,    // [B][N][HID] swizzled (key n&15)
    unsigned short* __restrict__ thetaT,  // [B][N][HID] swizzled (key n&15)
    unsigned short* __restrict__ gbuf)    // [B][HID][N] swizzled (key c&15)
{
    const int nt = blockIdx.x, p = blockIdx.y, b = blockIdx.z;
    const int n0 = nt * 128;
    const float* W = (p == 0) ? w_phi : (p == 1) ? w_theta : w_g;
    const float* X = x + (size_t)b * CIN * NPIX;

    __shared__ alignas(16) unsigned short Ws[128][40];
    __shared__ alignas(16) unsigned short Xs[128][40];

    const int tid = threadIdx.x;
    const int wave = tid >> 6, lane = tid & 63;
    const int wm = wave >> 1, wn = wave & 1;       // 2x2 waves over 128x128 tile
    const int quad = lane >> 4, l16 = lane & 15;

    f32x4 acc[4][4];
#pragma unroll
    for (int i = 0; i < 4; ++i)
#pragma unroll
        for (int j = 0; j < 4; ++j) acc[i][j] = {0.f, 0.f, 0.f, 0.f};

    for (int ks = 0; ks < CIN / 32; ++ks) {
        {   // stage W tile [128 o][32 c], f32 -> bf16 paired writes
            const int row = tid >> 1, c0 = (tid & 1) * 16;
            const float* src = W + (size_t)row * CIN + ks * 32 + c0;
            unsigned* dst = (unsigned*)&Ws[row][c0];
#pragma unroll
            for (int j = 0; j < 8; ++j) dst[j] = f2bf2(src[2 * j], src[2 * j + 1]);
        }
        {   // stage X^T tile: Xs[n][c] from X[c][n]; 2 c-rows x 8 n per thread
            const int cp = (tid >> 4) * 2, nn0 = (tid & 15) * 8;
            const float* s0 = X + (size_t)(ks * 32 + cp) * NPIX + n0 + nn0;
            const float* s1 = s0 + NPIX;
#pragma unroll
            for (int j = 0; j < 8; ++j)
                *(unsigned*)&Xs[nn0 + j][cp] = f2bf2(s0[j], s1[j]);
        }
        __syncthreads();
#pragma unroll
        for (int mi = 0; mi < 4; ++mi) {
            short8 a = *(const short8*)&Ws[wm * 64 + mi * 16 + l16][quad * 8];
#pragma unroll
            for (int ni = 0; ni < 4; ++ni) {
                short8 bb = *(const short8*)&Xs[wn * 64 + ni * 16 + l16][quad * 8];
                acc[mi][ni] = __builtin_amdgcn_mfma_f32_16x16x32_bf16(a, bb, acc[mi][ni], 0, 0, 0);
            }
        }
        __syncthreads();
    }

    if (p < 2) {   // store transposed + swizzled: T[b][n][scol(o)]
        unsigned short* T = (p == 0) ? phiT : thetaT;
#pragma unroll
        for (int mi = 0; mi < 4; ++mi) {
            const int obase = wm * 64 + mi * 16 + quad * 4;
#pragma unroll
            for (int ni = 0; ni < 4; ++ni) {
                const int nn = wn * 64 + ni * 16 + l16;
                const int scol = (((obase >> 3) ^ (nn & 15)) << 3) | (obase & 7);
                uint2 v;
                v.x = f2bf2(acc[mi][ni][0], acc[mi][ni][1]);
                v.y = f2bf2(acc[mi][ni][2], acc[mi][ni][3]);
                *(uint2*)&T[((size_t)b * NPIX + n0 + nn) * HIDN + scol] = v;
            }
        }
    } else {       // g stored [b][c][scol(n)] swizzled by c&15
#pragma unroll
        for (int mi = 0; mi < 4; ++mi) {
            const int obase = wm * 64 + mi * 16 + quad * 4;
#pragma unroll
            for (int ni = 0; ni < 4; ++ni) {
                const int nn = wn * 64 + ni * 16 + l16;
#pragma unroll
                for (int r = 0; r < 4; ++r) {
                    const int c = obase + r;
                    const int scol = n0 + ((((nn >> 3) ^ (c & 15)) << 3) | (nn & 7));
                    gbuf[((size_t)b * HIDN + c) * NPIX + scol] = f2bf(acc[mi][ni][r]);
                }
            }
        }
    }
}

// ---------------------------------------------------------------- K2: column sums of exp(S)
// grid (mt=32, ntg=8, b=4). phi tile DMA-staged ONCE, 4 theta chunks looped.
__global__ __launch_bounds__(256, 2) void k_colsum(
    const unsigned short* __restrict__ thetaT,
    const unsigned short* __restrict__ phiT,
    float* __restrict__ colsum)
{
    const int mt = blockIdx.x, ntg = blockIdx.y, b = blockIdx.z;
    const int m0 = mt * 128;
    __shared__ alignas(16) unsigned short As[128][128];   // theta [n][k] swizzled
    __shared__ alignas(16) unsigned short Bs[128][128];   // phi   [m][k] swizzled
    const int tid = threadIdx.x;
    const int wave = tid >> 6, lane = tid & 63;
    const int wm = wave >> 1, wn = wave & 1;
    const int quad = lane >> 4, l16 = lane & 15;

    {   // stage phi once: 32 KB linear copy (swizzle rides along)
        const unsigned short* src = phiT + ((size_t)b * NPIX + m0) * HIDN;
#pragma unroll
        for (int i = 0; i < 8; ++i) {
            const int u = i * 256 + tid;
            cp16(&Bs[0][0] + u * 8, src + u * 8);
        }
    }

    float csum[4] = {0.f, 0.f, 0.f, 0.f};

    for (int nc = 0; nc < 4; ++nc) {
        const int n0 = ntg * 512 + nc * 128;
        __syncthreads();   // prev MFMA done reading As (drains Bs DMA at nc==0)
        {
            const unsigned short* src = thetaT + ((size_t)b * NPIX + n0) * HIDN;
#pragma unroll
            for (int i = 0; i < 8; ++i) {
                const int u = i * 256 + tid;
                cp16(&As[0][0] + u * 8, src + u * 8);
            }
        }
        __syncthreads();

        f32x4 acc[4][4];
#pragma unroll
        for (int i = 0; i < 4; ++i)
#pragma unroll
            for (int j = 0; j < 4; ++j) acc[i][j] = {0.f, 0.f, 0.f, 0.f};

#pragma unroll
        for (int ks = 0; ks < 4; ++ks) {
            const int sc = (((ks * 4 + quad) ^ l16) << 3);   // swizzled k-granule
            short8 af[4], bf[4];
#pragma unroll
            for (int mi = 0; mi < 4; ++mi)
                af[mi] = *(const short8*)&As[wm * 64 + mi * 16 + l16][sc];
#pragma unroll
            for (int ni = 0; ni < 4; ++ni)
                bf[ni] = *(const short8*)&Bs[wn * 64 + ni * 16 + l16][sc];
#pragma unroll
            for (int mi = 0; mi < 4; ++mi)
#pragma unroll
                for (int ni = 0; ni < 4; ++ni)
                    acc[mi][ni] = __builtin_amdgcn_mfma_f32_16x16x32_bf16(af[mi], bf[ni], acc[mi][ni], 0, 0, 0);
        }
#pragma unroll
        for (int ni = 0; ni < 4; ++ni)
#pragma unroll
            for (int mi = 0; mi < 4; ++mi)
#pragma unroll
                for (int r = 0; r < 4; ++r) csum[ni] += __expf(acc[mi][ni][r]);
    }

#pragma unroll
    for (int ni = 0; ni < 4; ++ni) {
        float s = csum[ni];
        s += __shfl_xor(s, 16);
        s += __shfl_xor(s, 32);
        if (quad == 0)
            atomicAdd(&colsum[(size_t)b * NPIX + m0 + wn * 64 + ni * 16 + l16], s);
    }
}

__global__ void k_zero(float* __restrict__ p) { p[blockIdx.x * 256 + threadIdx.x] = 0.f; }
__global__ void k_zero4(float* __restrict__ p) {
    const size_t i = (size_t)(blockIdx.x * 256 + threadIdx.x) * 4;
    *(f32x4*)&p[i] = f32x4{0.f, 0.f, 0.f, 0.f};
}

// ---------------------------------------------------------------- K2b: g[c][m] *= 1/colsum[m]
__global__ __launch_bounds__(256) void k_scale_g(
    unsigned short* __restrict__ gbuf, const float* __restrict__ colsum)
{
    const int idx = blockIdx.x * 256 + threadIdx.x;   // 262144 granules
    const int row = idx >> 9;                          // b*128 + c
    const int sc = (idx & 511) * 8;                    // storage col (granule base)
    const int bb = row >> 7;
    // true m of this storage granule (un-swizzle)
    const int mt = (sc & ~127) | ((((sc >> 3) & 15) ^ (row & 15)) << 3);
    uint4 v = *(uint4*)&gbuf[(size_t)row * NPIX + sc];
    float4 c0 = *(const float4*)&colsum[(size_t)bb * NPIX + mt];
    float4 c1 = *(const float4*)&colsum[(size_t)bb * NPIX + mt + 4];
    unsigned short* vs = (unsigned short*)&v;
    const float cs[8] = {c0.x, c0.y, c0.z, c0.w, c1.x, c1.y, c1.z, c1.w};
#pragma unroll
    for (int j = 0; j < 8; ++j) vs[j] = f2bf(bf2f(vs[j]) / cs[j]);
    *(uint4*)&gbuf[(size_t)row * NPIX + sc] = v;
}

// ---------------------------------------------------------------- K3: O += exp(S) @ g'^T
// grid (nt=64, ms=2, b=4) = 512 blocks = 2/CU. 32x32x16 MFMA, 128-m chunks.
__global__ __launch_bounds__(256, 2) void k_attn(
    const unsigned short* __restrict__ thetaT,
    const unsigned short* __restrict__ phiT,
    const unsigned short* __restrict__ gbuf,   // pre-scaled by 1/colsum
    float* __restrict__ O32)                   // [B][N][HID] fp32, zeroed
{
    const int nt = blockIdx.x, ms = blockIdx.y, b = blockIdx.z;
    const int n0 = nt * 64;

    __shared__ alignas(16) unsigned short Bs[128][128];  // phi chunk [m][k] swizzled
    __shared__ alignas(16) unsigned short Gs[128][128];  // g'  chunk [c][m] swizzled
    __shared__ alignas(16) unsigned short Ps[64][128];   // P [n][m] swizzled (key n&15)
    // total LDS = 80 KB -> 2 blocks/CU

    const int tid = threadIdx.x;
    const int wave = tid >> 6, lane = tid & 63;
    const int wm = wave >> 1, wn = wave & 1;   // wm: n-half; wn: m-half (S) / c-half (PV)
    const int l31 = lane & 31, lh = lane >> 5;
    const int key = l31 & 15;

    // theta A-fragments register-resident (32 rows n, full K=128, swizzled global)
    short8 afrag[8];
    {
        const int n = n0 + wm * 32 + l31;
        const unsigned short* src = thetaT + ((size_t)b * NPIX + n) * HIDN;
#pragma unroll
        for (int ks = 0; ks < 8; ++ks)
            afrag[ks] = *(const short8*)(src + (((ks * 2 + lh) ^ key) << 3));
    }

    f32x16 accO[2];
#pragma unroll
    for (int r = 0; r < 16; ++r) { accO[0][r] = 0.f; accO[1][r] = 0.f; }

    for (int mc = 0; mc < 16; ++mc) {
        const int m0 = (ms * 16 + mc) * 128;
        __syncthreads();   // prev chunk's PV done reading Gs/Ps, S done reading Bs
        {   // stage phi chunk: 32 KB linear DMA
            const unsigned short* src = phiT + ((size_t)b * NPIX + m0) * HIDN;
#pragma unroll
            for (int i = 0; i < 8; ++i) {
                const int u = i * 256 + tid;
                cp16(&Bs[0][0] + u * 8, src + u * 8);
            }
        }
        {   // stage g' chunk: 128 rows x 256B DMA
#pragma unroll
            for (int i = 0; i < 8; ++i) {
                const int u = i * 256 + tid;
                const int row = u >> 4, un = u & 15;
                cp16(&Gs[0][0] + u * 8,
                     gbuf + ((size_t)b * HIDN + row) * NPIX + m0 + un * 8);
            }
        }
        __syncthreads();

        // ---- S tile [64 n][128 m], K=128, 32x32x16
        f32x16 accS[2];
#pragma unroll
        for (int r = 0; r < 16; ++r) { accS[0][r] = 0.f; accS[1][r] = 0.f; }
#pragma unroll
        for (int ks = 0; ks < 8; ++ks) {
            const int sc = ((ks * 2 + lh) ^ key) << 3;
            short8 b0 = *(const short8*)&Bs[wn * 64 + l31][sc];
            short8 b1 = *(const short8*)&Bs[wn * 64 + 32 + l31][sc];
            accS[0] = __builtin_amdgcn_mfma_f32_32x32x16_bf16(afrag[ks], b0, accS[0], 0, 0, 0);
            accS[1] = __builtin_amdgcn_mfma_f32_32x32x16_bf16(afrag[ks], b1, accS[1], 0, 0, 0);
        }
        // ---- P = exp(S) -> Ps (C/D layout -> A layout, swizzled)
#pragma unroll
        for (int ni = 0; ni < 2; ++ni) {
            const int m_loc = wn * 64 + ni * 32 + l31;
#pragma unroll
            for (int r = 0; r < 16; ++r) {
                const int n_loc = wm * 32 + (r & 3) + 8 * (r >> 2) + 4 * lh;
                const int scol = (((m_loc >> 3) ^ (n_loc & 15)) << 3) | (m_loc & 7);
                Ps[n_loc][scol] = f2bf(__expf(accS[ni][r]));
            }
        }
        __syncthreads();
        // ---- O tile [64 n][128 c] += P @ g'^T, K=128 (m chunk)
        {
            const int prow = wm * 32 + l31;
            const int pkey = prow & 15;
#pragma unroll
            for (int ks = 0; ks < 8; ++ks) {
                const int sc = ((ks * 2 + lh) ^ key) << 3;
                short8 pa = *(const short8*)&Ps[prow][((ks * 2 + lh) ^ pkey) << 3];
                short8 g0 = *(const short8*)&Gs[wn * 64 + l31][sc];
                short8 g1 = *(const short8*)&Gs[wn * 64 + 32 + l31][sc];
                accO[0] = __builtin_amdgcn_mfma_f32_32x32x16_bf16(pa, g0, accO[0], 0, 0, 0);
                accO[1] = __builtin_amdgcn_mfma_f32_32x32x16_bf16(pa, g1, accO[1], 0, 0, 0);
            }
        }
    }

#pragma unroll
    for (int ni = 0; ni < 2; ++ni)
#pragma unroll
        for (int r = 0; r < 16; ++r) {
            const int n = n0 + wm * 32 + (r & 3) + 8 * (r >> 2) + 4 * lh;
            const int c = wn * 64 + ni * 32 + l31;
            atomicAdd(&O32[((size_t)b * NPIX + n) * HIDN + c], accO[ni][r]);
        }
}

// ---------------------------------------------------------------- K4: mask GEMM + residual
__global__ __launch_bounds__(256) void k_mask(
    const float* __restrict__ w_mask,      // [256][128]
    const float* __restrict__ O32,         // [B][N][HID] fp32 (not swizzled)
    const float* __restrict__ x,
    float* __restrict__ out)
{
    const int nt = blockIdx.x, ct = blockIdx.y, b = blockIdx.z;
    const int n0 = nt * 128, c0 = ct * 128;
    __shared__ alignas(16) unsigned short As[128][40];
    __shared__ alignas(16) unsigned short Bs[128][40];
    const int tid = threadIdx.x;
    const int wave = tid >> 6, lane = tid & 63;
    const int wm = wave >> 1, wn = wave & 1;
    const int quad = lane >> 4, l16 = lane & 15;

    f32x4 acc[4][4];
#pragma unroll
    for (int i = 0; i < 4; ++i)
#pragma unroll
        for (int j = 0; j < 4; ++j) acc[i][j] = {0.f, 0.f, 0.f, 0.f};

    for (int ks = 0; ks < 4; ++ks) {
        {   // A: w_mask tile [128 co][32 h], paired bf16 writes
            const int row = tid >> 1, cc0 = (tid & 1) * 16;
            const float* src = w_mask + (size_t)(c0 + row) * HIDN + ks * 32 + cc0;
            unsigned* dst = (unsigned*)&As[row][cc0];
#pragma unroll
            for (int j = 0; j < 8; ++j) dst[j] = f2bf2(src[2 * j], src[2 * j + 1]);
        }
        {   // B: O32 tile [128 n][32 h], paired bf16 writes
            const int row = tid >> 1, h0 = (tid & 1) * 16;
            const float* src = O32 + ((size_t)b * NPIX + n0 + row) * HIDN + ks * 32 + h0;
            unsigned* dst = (unsigned*)&Bs[row][h0];
#pragma unroll
            for (int j = 0; j < 8; ++j) dst[j] = f2bf2(src[2 * j], src[2 * j + 1]);
        }
        __syncthreads();
#pragma unroll
        for (int mi = 0; mi < 4; ++mi) {
            short8 a = *(const short8*)&As[wm * 64 + mi * 16 + l16][quad * 8];
#pragma unroll
            for (int ni = 0; ni < 4; ++ni) {
                short8 bb = *(const short8*)&Bs[wn * 64 + ni * 16 + l16][quad * 8];
                acc[mi][ni] = __builtin_amdgcn_mfma_f32_16x16x32_bf16(a, bb, acc[mi][ni], 0, 0, 0);
            }
        }
        __syncthreads();
    }

#pragma unroll
    for (int mi = 0; mi < 4; ++mi)
#pragma unroll
        for (int ni = 0; ni < 4; ++ni)
#pragma unroll
            for (int r = 0; r < 4; ++r) {
                const int co = c0 + wm * 64 + mi * 16 + quad * 4 + r;
                const int nn = n0 + wn * 64 + ni * 16 + l16;
                const size_t idx = ((size_t)b * CIN + co) * NPIX + nn;
                out[idx] = acc[mi][ni][r] + x[idx];
            }
}

// ---------------------------------------------------------------- launch
extern "C" void kernel_launch(void* const* d_in, const int* in_sizes, int n_in,
                              void* d_out, int out_size, void* d_ws, size_t ws_size,
                              hipStream_t stream)
{
    (void)in_sizes; (void)n_in; (void)out_size; (void)ws_size;
    const float* x       = (const float*)d_in[0];
    const float* w_phi   = (const float*)d_in[1];
    const float* w_theta = (const float*)d_in[2];
    const float* w_g     = (const float*)d_in[3];
    const float* w_mask  = (const float*)d_in[4];
    float* out = (float*)d_out;

    char* ws = (char*)d_ws;
    unsigned short* phiT   = (unsigned short*)(ws);              //  4 MB
    unsigned short* thetaT = (unsigned short*)(ws + 4194304);    //  4 MB
    unsigned short* gbuf   = (unsigned short*)(ws + 8388608);    //  4 MB
    float*          colsum = (float*)(ws + 12582912);            // 64 KB
    float*          O32    = (float*)(ws + 12648448);            //  8 MB
    // total ws use: 21,037,056 bytes

    k_proj   <<<dim3(32, 3, 4), 256, 0, stream>>>(x, w_phi, w_theta, w_g, phiT, thetaT, gbuf);
    k_zero   <<<dim3(64),       256, 0, stream>>>(colsum);
    k_zero4  <<<dim3(2048),     256, 0, stream>>>(O32);
    k_colsum <<<dim3(32, 8, 4), 256, 0, stream>>>(thetaT, phiT, colsum);
    k_scale_g<<<dim3(1024),     256, 0, stream>>>(gbuf, colsum);
    k_attn   <<<dim3(64, 2, 4), 256, 0, stream>>>(thetaT, phiT, gbuf, O32);
    k_mask   <<<dim3(32, 2, 4), 256, 0, stream>>>(w_mask, O32, x, out);
}

// Round 4
// 186.454 us; speedup vs baseline: 1.3007x; 1.0004x over previous
//
#include <hip/hip_runtime.h>

// NonLocalBlock: B=4, C=256, HID=128, N=64*64=4096, all-f32 in/out.
// Pipeline (bf16 MFMA 32x32x16, fp32 accum):
//   P1 k_prep_w : w_phi/theta/g/mask -> bf16, granule-swizzled (key o&15)
//   P2 k_prep_x : x -> xT[b][n][256] bf16 swizzled (key n&15); zero colsum
//   K1 k_proj   : phiT/thetaT[b][n][128] (key n&15), gbuf[b][c][n] (key c&7)
//   K2 k_colsum : colsum[b][m] = sum_n exp(S[n][m]); also zeroes O32
//   K2b k_scale_g: g[c][m] *= 1/colsum[m]
//   K3 k_attn   : O32[b][n][c] += sum_m exp(S[n][m]) * g'[c][m]
//                 (64-m chunks, 40 KB LDS -> 4 blocks/CU, DMA staging,
//                  register theta A-frags, swizzled Ps round-trip, ms-split x4)
//   K4 k_mask   : out = w_mask @ O^T + x  (DMA A-stage, single K pass)
// Swizzles: SW16 (128-col sections): sc = (c&~127)|((((c>>3)&15)^(k&15))<<3)|(c&7)
//           SW8  (64-col groups)   : sc = (c&~63) |((((c>>3)&7 )^(k&7 ))<<3)|(c&7)
// ws: phiT(4M) thetaT(4M) gbuf(4M) colsum(64K) XO=xT|O32(8M, aliased) W(256K)

#define NB   4
#define CIN  256
#define HIDN 128
#define NPIX 4096

typedef __attribute__((ext_vector_type(8))) short short8;
typedef __attribute__((ext_vector_type(4))) float f32x4;
typedef __attribute__((ext_vector_type(16))) float f32x16;

__device__ __forceinline__ unsigned short f2bf(float f) {
    unsigned u = __builtin_bit_cast(unsigned, f);
    u += 0x7fffu + ((u >> 16) & 1u);          // RNE; inputs finite
    return (unsigned short)(u >> 16);
}
__device__ __forceinline__ unsigned f2bf2(float lo, float hi) {
    return (unsigned)f2bf(lo) | ((unsigned)f2bf(hi) << 16);
}
__device__ __forceinline__ float bf2f(unsigned short s) {
    return __builtin_bit_cast(float, (unsigned)s << 16);
}
// async global->LDS, 16B/lane; LDS dest = wave-uniform base + lane*16
__device__ __forceinline__ void cp16(void* lds, const void* g) {
    __builtin_amdgcn_global_load_lds(
        (const __attribute__((address_space(1))) unsigned int*)g,
        (__attribute__((address_space(3))) unsigned int*)lds, 16, 0, 0);
}

// ---------------------------------------------------------------- P1: W conversion
// 32 blocks: [0,8) w_phi, [8,16) w_theta, [16,24) w_g, [24,32) w_mask.
__global__ __launch_bounds__(256) void k_prep_w(
    const float* __restrict__ wp, const float* __restrict__ wt,
    const float* __restrict__ wg, const float* __restrict__ wm,
    unsigned short* __restrict__ Wp, unsigned short* __restrict__ Wt,
    unsigned short* __restrict__ Wg, unsigned short* __restrict__ Wm)
{
    const int which = blockIdx.x >> 3;
    const float* src = (which == 0) ? wp : (which == 1) ? wt : (which == 2) ? wg : wm;
    unsigned short* dst = (which == 0) ? Wp : (which == 1) ? Wt : (which == 2) ? Wg : Wm;
#pragma unroll
    for (int t = 0; t < 2; ++t) {
        const int gidx = ((blockIdx.x & 7) * 256 + threadIdx.x) * 2 + t;  // 4096 granules
        int o, srcc, dstc;
        if (which < 3) {                       // [128][256]
            o = gidx >> 5;
            const int gc = gidx & 31;
            const int sg = (gc & ~15) | ((gc & 15) ^ (o & 15));
            srcc = o * 256 + gc * 8; dstc = o * 256 + sg * 8;
        } else {                               // [256][128]
            o = gidx >> 4;
            const int gc = gidx & 15;
            const int sg = gc ^ (o & 15);
            srcc = o * 128 + gc * 8; dstc = o * 128 + sg * 8;
        }
        float4 a = *(const float4*)&src[srcc];
        float4 b = *(const float4*)&src[srcc + 4];
        uint4 v;
        v.x = f2bf2(a.x, a.y); v.y = f2bf2(a.z, a.w);
        v.z = f2bf2(b.x, b.y); v.w = f2bf2(b.z, b.w);
        *(uint4*)&dst[dstc] = v;
    }
}

// ---------------------------------------------------------------- P2: x -> xT bf16 swizzled
// grid (nt=64, ct=4, b=4). Tile [64 c][64 n]. Also zeroes colsum (ct==0 blocks).
__global__ __launch_bounds__(256) void k_prep_x(
    const float* __restrict__ x,
    unsigned short* __restrict__ xT,   // [B][N][256] SW16 key n&15
    float* __restrict__ colsum)
{
    const int nt = blockIdx.x, ct = blockIdx.y, b = blockIdx.z;
    const int tid = threadIdx.x;
    if (ct == 0 && tid < 64) colsum[(size_t)b * NPIX + nt * 64 + tid] = 0.f;

    __shared__ unsigned short Ls[64][66];
    {   // read x tile [64 c][64 n] coalesced, convert, store LDS transposed-src layout
        const int c_loc = tid >> 2, n_seg = (tid & 3) * 16;
        const float* src = x + ((size_t)(b * CIN + ct * 64 + c_loc)) * NPIX + nt * 64 + n_seg;
#pragma unroll
        for (int j = 0; j < 8; ++j)
            *(unsigned*)&Ls[c_loc][n_seg + 2 * j] = f2bf2(src[2 * j], src[2 * j + 1]);
    }
    __syncthreads();
    {   // write xT rows: thread handles row n_loc, 16 c values (2 granules)
        const int n_loc = tid >> 2, c_seg = (tid & 3) * 16;
        const int n_glob = nt * 64 + n_loc;
        unsigned short tmp[16];
#pragma unroll
        for (int j = 0; j < 16; ++j) tmp[j] = Ls[c_seg + j][n_loc];
#pragma unroll
        for (int gr = 0; gr < 2; ++gr) {
            const int c_base = ct * 64 + c_seg + gr * 8;
            const int sec = c_base >> 7;
            const int sg = (((c_base >> 3) & 15) ^ (n_glob & 15));
            *(uint4*)&xT[((size_t)b * NPIX + n_glob) * CIN + sec * 128 + sg * 8] =
                *(uint4*)&tmp[gr * 8];
        }
    }
}

// ---------------------------------------------------------------- K1: projections (GEMM)
// grid (nt=64, ot=3, b=4) = 768 = 3/CU. Block tile [128 o][64 n], K=256 in 2 halves.
__global__ __launch_bounds__(256, 3) void k_proj(
    const unsigned short* __restrict__ Wp,   // [128][256] bf16 SW16 key o&15
    const unsigned short* __restrict__ Wt,
    const unsigned short* __restrict__ Wg,
    const unsigned short* __restrict__ xT,   // [B][N][256] SW16 key n&15
    unsigned short* __restrict__ phiT,       // [B][N][128] SW16 key n&15
    unsigned short* __restrict__ thetaT,
    unsigned short* __restrict__ gbuf)       // [B][128][N] SW8 key c&7
{
    const int nt = blockIdx.x, ot = blockIdx.y, b = blockIdx.z;
    const unsigned short* W = (ot == 0) ? Wp : (ot == 1) ? Wt : Wg;

    __shared__ alignas(16) unsigned short Aw[128][128];  // W k-half
    __shared__ alignas(16) unsigned short Bx[64][128];   // xT k-half

    const int tid = threadIdx.x;
    const int wave = tid >> 6, lane = tid & 63;
    const int oh = wave >> 1, nh = wave & 1;
    const int l31 = lane & 31, lh = lane >> 5;
    const int key = l31 & 15;

    f32x16 acc[2];
#pragma unroll
    for (int r = 0; r < 16; ++r) { acc[0][r] = 0.f; acc[1][r] = 0.f; }

    for (int kh = 0; kh < 2; ++kh) {
        __syncthreads();
#pragma unroll
        for (int i = 0; i < 8; ++i) {   // Aw: 128 rows x 128 shorts
            const int u = i * 256 + tid;
            cp16(&Aw[0][0] + u * 8, W + (u >> 4) * 256 + kh * 128 + (u & 15) * 8);
        }
#pragma unroll
        for (int i = 0; i < 4; ++i) {   // Bx: 64 rows x 128 shorts
            const int u = i * 256 + tid;
            cp16(&Bx[0][0] + u * 8,
                 xT + ((size_t)b * NPIX + nt * 64 + (u >> 4)) * CIN + kh * 128 + (u & 15) * 8);
        }
        __syncthreads();
#pragma unroll
        for (int ks = 0; ks < 8; ++ks) {
            const int g = ((ks * 2 + lh) ^ key) << 3;
            short8 bb = *(const short8*)&Bx[nh * 32 + l31][g];
#pragma unroll
            for (int t = 0; t < 2; ++t) {
                short8 a = *(const short8*)&Aw[oh * 64 + t * 32 + l31][g];
                acc[t] = __builtin_amdgcn_mfma_f32_32x32x16_bf16(a, bb, acc[t], 0, 0, 0);
            }
        }
    }

    const int n_glob = nt * 64 + nh * 32 + l31;
    if (ot < 2) {
        unsigned short* T = (ot == 0) ? phiT : thetaT;
#pragma unroll
        for (int t = 0; t < 2; ++t)
#pragma unroll
            for (int rg = 0; rg < 4; ++rg) {
                const int ob = oh * 64 + t * 32 + 8 * rg + 4 * lh;   // 4 consecutive o
                const int sc = (((ob >> 3) ^ (n_glob & 15)) << 3) | (ob & 7);
                uint2 v;
                v.x = f2bf2(acc[t][rg * 4 + 0], acc[t][rg * 4 + 1]);
                v.y = f2bf2(acc[t][rg * 4 + 2], acc[t][rg * 4 + 3]);
                *(uint2*)&T[((size_t)b * NPIX + n_glob) * HIDN + sc] = v;
            }
    } else {
        const int sbase = n_glob & ~63;
        const int g8 = (n_glob >> 3) & 7, c7off = n_glob & 7;
#pragma unroll
        for (int t = 0; t < 2; ++t)
#pragma unroll
            for (int r = 0; r < 16; ++r) {
                const int c = oh * 64 + t * 32 + (r & 3) + 8 * (r >> 2) + 4 * lh;
                const int sc = sbase | (((g8 ^ (c & 7)) << 3)) | c7off;
                gbuf[((size_t)b * HIDN + c) * NPIX + sc] = f2bf(acc[t][r]);
            }
    }
}

// ---------------------------------------------------------------- K2: colsum (+ zero O32)
// grid (mt=32, ng=8, b=4) = 1024. phi B-frags in registers; theta DMA chunks of 64 n.
__global__ __launch_bounds__(256, 3) void k_colsum(
    const unsigned short* __restrict__ thetaT,
    const unsigned short* __restrict__ phiT,
    float* __restrict__ colsum,
    float* __restrict__ O32)
{
    const int mt = blockIdx.x, ng = blockIdx.y, b = blockIdx.z;
    const int tid = threadIdx.x;
    {   // zero O32: 2048 floats per block
        const int blin = ((blockIdx.z * 8 + blockIdx.y) * 32 + blockIdx.x);
        float* p = O32 + (size_t)blin * 2048 + tid * 8;
        *(f32x4*)p = f32x4{0.f, 0.f, 0.f, 0.f};
        *(f32x4*)(p + 4) = f32x4{0.f, 0.f, 0.f, 0.f};
    }

    __shared__ alignas(16) unsigned short As[64][128];   // theta chunk

    const int wave = tid >> 6, lane = tid & 63;
    const int wn = wave & 1, wh = wave >> 1;
    const int l31 = lane & 31, lh = lane >> 5;
    const int key = l31 & 15;

    short8 bfrag[2][8];   // phi, m-half wn*64, 2 tiles x K=128
#pragma unroll
    for (int t = 0; t < 2; ++t) {
        const int m = mt * 128 + wn * 64 + t * 32 + l31;
        const unsigned short* src = phiT + ((size_t)b * NPIX + m) * HIDN;
#pragma unroll
        for (int ks = 0; ks < 8; ++ks)
            bfrag[t][ks] = *(const short8*)(src + (((ks * 2 + lh) ^ key) << 3));
    }

    float csum[2] = {0.f, 0.f};

    for (int nc = 0; nc < 8; ++nc) {
        const int n0 = ng * 512 + nc * 64;
        __syncthreads();
#pragma unroll
        for (int i = 0; i < 4; ++i) {
            const int u = i * 256 + tid;
            cp16(&As[0][0] + u * 8,
                 thetaT + ((size_t)b * NPIX + n0 + (u >> 4)) * HIDN + (u & 15) * 8);
        }
        __syncthreads();

        f32x16 acc[2];
#pragma unroll
        for (int r = 0; r < 16; ++r) { acc[0][r] = 0.f; acc[1][r] = 0.f; }
#pragma unroll
        for (int ks = 0; ks < 8; ++ks) {
            short8 a = *(const short8*)&As[wh * 32 + l31][(((ks * 2 + lh) ^ key) << 3)];
            acc[0] = __builtin_amdgcn_mfma_f32_32x32x16_bf16(a, bfrag[0][ks], acc[0], 0, 0, 0);
            acc[1] = __builtin_amdgcn_mfma_f32_32x32x16_bf16(a, bfrag[1][ks], acc[1], 0, 0, 0);
        }
#pragma unroll
        for (int t = 0; t < 2; ++t)
#pragma unroll
            for (int r = 0; r < 16; ++r) csum[t] += __expf(acc[t][r]);
    }

#pragma unroll
    for (int t = 0; t < 2; ++t) {
        float s = csum[t];
        s += __shfl_xor(s, 32);   // combine lh halves (row sets offset by 4)
        if (lh == 0)
            atomicAdd(&colsum[(size_t)b * NPIX + mt * 128 + wn * 64 + t * 32 + l31], s);
    }
}

// ---------------------------------------------------------------- K2b: g[c][m] *= 1/colsum[m]
__global__ __launch_bounds__(256) void k_scale_g(
    unsigned short* __restrict__ gbuf, const float* __restrict__ colsum)
{
    const int idx = blockIdx.x * 256 + threadIdx.x;   // 262144 granules
    const int row = idx >> 9;                          // b*128 + c
    const int sc = (idx & 511) * 8;                    // storage col (granule base)
    const int bb = row >> 7;
    // un-swizzle (SW8, key c&7): true m granule base
    const int mt = (sc & ~63) | (((((sc >> 3) & 7) ^ (row & 7))) << 3);
    uint4 v = *(uint4*)&gbuf[(size_t)row * NPIX + sc];
    float4 c0 = *(const float4*)&colsum[(size_t)bb * NPIX + mt];
    float4 c1 = *(const float4*)&colsum[(size_t)bb * NPIX + mt + 4];
    unsigned short* vs = (unsigned short*)&v;
    const float cs[8] = {c0.x, c0.y, c0.z, c0.w, c1.x, c1.y, c1.z, c1.w};
#pragma unroll
    for (int j = 0; j < 8; ++j) vs[j] = f2bf(bf2f(vs[j]) / cs[j]);
    *(uint4*)&gbuf[(size_t)row * NPIX + sc] = v;
}

// ---------------------------------------------------------------- K3: O += exp(S) @ g'^T
// grid (nt=64, ms=4, b=4) = 1024 = 4/CU at 40 KB LDS. 64-m chunks.
__global__ __launch_bounds__(256, 4) void k_attn(
    const unsigned short* __restrict__ thetaT,
    const unsigned short* __restrict__ phiT,
    const unsigned short* __restrict__ gbuf,   // pre-scaled by 1/colsum
    float* __restrict__ O32)                   // [B][N][HID] fp32, zeroed
{
    const int nt = blockIdx.x, ms = blockIdx.y, b = blockIdx.z;
    const int n0 = nt * 64;

    __shared__ alignas(16) unsigned short Bs[64][128];   // phi [m][k] SW16
    __shared__ alignas(16) unsigned short Gs[128][64];   // g'  [c][m] SW8
    __shared__ alignas(16) unsigned short Ps[64][64];    // P   [n][m] SW8 key n&7

    const int tid = threadIdx.x;
    const int wave = tid >> 6, lane = tid & 63;
    const int wm = wave >> 1, wn = wave & 1;   // wm: n-half32; wn: m-tile32 (S) / c-half64 (PV)
    const int l31 = lane & 31, lh = lane >> 5;
    const int key = l31 & 15, key7 = l31 & 7;

    short8 afrag[8];   // theta rows n0 + wm*32 + l31, K=128
    {
        const unsigned short* src = thetaT + ((size_t)b * NPIX + n0 + wm * 32 + l31) * HIDN;
#pragma unroll
        for (int ks = 0; ks < 8; ++ks)
            afrag[ks] = *(const short8*)(src + (((ks * 2 + lh) ^ key) << 3));
    }

    f32x16 accO[2];
#pragma unroll
    for (int r = 0; r < 16; ++r) { accO[0][r] = 0.f; accO[1][r] = 0.f; }

    for (int mc = 0; mc < 16; ++mc) {
        const int m0 = (ms * 16 + mc) * 64;
        __syncthreads();
#pragma unroll
        for (int i = 0; i < 4; ++i) {   // Bs: 64 m-rows x 128 k
            const int u = i * 256 + tid;
            cp16(&Bs[0][0] + u * 8,
                 phiT + ((size_t)b * NPIX + m0 + (u >> 4)) * HIDN + (u & 15) * 8);
        }
#pragma unroll
        for (int i = 0; i < 4; ++i) {   // Gs: 128 c-rows x 64 m
            const int u = i * 256 + tid;
            cp16(&Gs[0][0] + u * 8,
                 gbuf + ((size_t)b * HIDN + (u >> 3)) * NPIX + m0 + (u & 7) * 8);
        }
        __syncthreads();

        // ---- S tile: wave computes [32 n][32 m], K=128
        f32x16 accS;
#pragma unroll
        for (int r = 0; r < 16; ++r) accS[r] = 0.f;
#pragma unroll
        for (int ks = 0; ks < 8; ++ks) {
            short8 bb = *(const short8*)&Bs[wn * 32 + l31][(((ks * 2 + lh) ^ key) << 3)];
            accS = __builtin_amdgcn_mfma_f32_32x32x16_bf16(afrag[ks], bb, accS, 0, 0, 0);
        }
        // ---- P = exp(S) -> Ps (C/D -> A layout, SW8 key n&7)
        {
            const int m_loc = wn * 32 + l31;
#pragma unroll
            for (int r = 0; r < 16; ++r) {
                const int n_loc = wm * 32 + (r & 3) + 8 * (r >> 2) + 4 * lh;
                const int sc = (((m_loc >> 3) ^ (n_loc & 7)) << 3) | (m_loc & 7);
                Ps[n_loc][sc] = f2bf(__expf(accS[r]));
            }
        }
        __syncthreads();
        // ---- O tile [64 n][128 c] += P @ g'^T, K=64
#pragma unroll
        for (int ks = 0; ks < 4; ++ks) {
            const int g = ((ks * 2 + lh) ^ key7) << 3;
            short8 pa = *(const short8*)&Ps[wm * 32 + l31][g];
            short8 g0 = *(const short8*)&Gs[wn * 64 + l31][g];
            short8 g1 = *(const short8*)&Gs[wn * 64 + 32 + l31][g];
            accO[0] = __builtin_amdgcn_mfma_f32_32x32x16_bf16(pa, g0, accO[0], 0, 0, 0);
            accO[1] = __builtin_amdgcn_mfma_f32_32x32x16_bf16(pa, g1, accO[1], 0, 0, 0);
        }
    }

#pragma unroll
    for (int t = 0; t < 2; ++t)
#pragma unroll
        for (int r = 0; r < 16; ++r) {
            const int n = n0 + wm * 32 + (r & 3) + 8 * (r >> 2) + 4 * lh;
            const int c = wn * 64 + t * 32 + l31;
            atomicAdd(&O32[((size_t)b * NPIX + n) * HIDN + c], accO[t][r]);
        }
}

// ---------------------------------------------------------------- K4: mask GEMM + residual
// grid (nt=64, ct=2, b=4) = 512. Block tile [128 co][64 n], single K=128 pass.
__global__ __launch_bounds__(256, 3) void k_mask(
    const unsigned short* __restrict__ Wm,   // [256][128] bf16 SW16 key o&15
    const float* __restrict__ O32,           // [B][N][HID] fp32 plain
    const float* __restrict__ x,
    float* __restrict__ out)
{
    const int nt = blockIdx.x, ct = blockIdx.y, b = blockIdx.z;
    __shared__ alignas(16) unsigned short As[128][128];  // w_mask rows SW16
    __shared__ alignas(16) unsigned short Bs[64][128];   // O bf16, SW8 key n&7

    const int tid = threadIdx.x;
    const int wave = tid >> 6, lane = tid & 63;
    const int oh = wave >> 1, nh = wave & 1;
    const int l31 = lane & 31, lh = lane >> 5;
    const int key = l31 & 15;

#pragma unroll
    for (int i = 0; i < 8; ++i) {   // As DMA: 128 rows x 128
        const int u = i * 256 + tid;
        cp16(&As[0][0] + u * 8, Wm + (ct * 128 + (u >> 4)) * HIDN + (u & 15) * 8);
    }
    {   // Bs: convert O32 [64 n][128 h] -> bf16 SW8(n&7)
        const int n_loc = tid >> 2, seg = (tid & 3) * 32;
        const float* src = O32 + ((size_t)b * NPIX + nt * 64 + n_loc) * HIDN + seg;
        const int k7 = n_loc & 7;
#pragma unroll
        for (int j = 0; j < 4; ++j) {          // 4 granules of 8
            const int gr = (seg >> 3) + j;
            const int sg = (gr & ~7) | ((gr & 7) ^ k7);
            const float* s8 = src + j * 8;
            unsigned* d = (unsigned*)&Bs[n_loc][sg * 8];
#pragma unroll
            for (int k = 0; k < 4; ++k) d[k] = f2bf2(s8[2 * k], s8[2 * k + 1]);
        }
    }
    __syncthreads();

    f32x16 acc[2];
#pragma unroll
    for (int r = 0; r < 16; ++r) { acc[0][r] = 0.f; acc[1][r] = 0.f; }
#pragma unroll
    for (int ks = 0; ks < 8; ++ks) {
        const int gr = ks * 2 + lh;
        const int sgb = ((gr & ~7) | ((gr & 7) ^ (l31 & 7))) << 3;
        short8 bb = *(const short8*)&Bs[nh * 32 + l31][sgb];
#pragma unroll
        for (int t = 0; t < 2; ++t) {
            short8 a = *(const short8*)&As[oh * 64 + t * 32 + l31][((gr ^ key) << 3)];
            acc[t] = __builtin_amdgcn_mfma_f32_32x32x16_bf16(a, bb, acc[t], 0, 0, 0);
        }
    }

    const int n = nt * 64 + nh * 32 + l31;
#pragma unroll
    for (int t = 0; t < 2; ++t)
#pragma unroll
        for (int r = 0; r < 16; ++r) {
            const int co = ct * 128 + oh * 64 + t * 32 + (r & 3) + 8 * (r >> 2) + 4 * lh;
            const size_t idx = ((size_t)b * CIN + co) * NPIX + n;
            out[idx] = acc[t][r] + x[idx];
        }
}

// ---------------------------------------------------------------- launch
extern "C" void kernel_launch(void* const* d_in, const int* in_sizes, int n_in,
                              void* d_out, int out_size, void* d_ws, size_t ws_size,
                              hipStream_t stream)
{
    (void)in_sizes; (void)n_in; (void)out_size; (void)ws_size;
    const float* x       = (const float*)d_in[0];
    const float* w_phi   = (const float*)d_in[1];
    const float* w_theta = (const float*)d_in[2];
    const float* w_g     = (const float*)d_in[3];
    const float* w_mask  = (const float*)d_in[4];
    float* out = (float*)d_out;

    char* ws = (char*)d_ws;
    unsigned short* phiT   = (unsigned short*)(ws);              //  4 MB
    unsigned short* thetaT = (unsigned short*)(ws + 4194304);    //  4 MB
    unsigned short* gbuf   = (unsigned short*)(ws + 8388608);    //  4 MB
    float*          colsum = (float*)(ws + 12582912);            // 64 KB
    // xT (bf16, prep->proj) and O32 (fp32, colsum->mask) alias: xT dead after k_proj,
    // O32 zeroed inside k_colsum which runs after k_proj.
    unsigned short* xT     = (unsigned short*)(ws + 12648448);   //  8 MB
    float*          O32    = (float*)(ws + 12648448);
    unsigned short* Wp     = (unsigned short*)(ws + 21037056);   // 64 KB
    unsigned short* Wt     = (unsigned short*)(ws + 21102592);   // 64 KB
    unsigned short* Wg     = (unsigned short*)(ws + 21168128);   // 64 KB
    unsigned short* Wm     = (unsigned short*)(ws + 21233664);   // 64 KB
    // total ws use: 21,299,200 bytes

    k_prep_w <<<dim3(32),        256, 0, stream>>>(w_phi, w_theta, w_g, w_mask, Wp, Wt, Wg, Wm);
    k_prep_x <<<dim3(64, 4, 4),  256, 0, stream>>>(x, xT, colsum);
    k_proj   <<<dim3(64, 3, 4),  256, 0, stream>>>(Wp, Wt, Wg, xT, phiT, thetaT, gbuf);
    k_colsum <<<dim3(32, 8, 4),  256, 0, stream>>>(thetaT, phiT, colsum, O32);
    k_scale_g<<<dim3(1024),      256, 0, stream>>>(gbuf, colsum);
    k_attn   <<<dim3(64, 4, 4),  256, 0, stream>>>(thetaT, phiT, gbuf, O32);
    k_mask   <<<dim3(64, 2, 4),  256, 0, stream>>>(Wm, O32, x, out);
}